// Round 1
// baseline (18511.848 us; speedup 1.0000x reference)
//
#include <hip/hip_runtime.h>
#include <hip/hip_fp16.h>

typedef _Float16 f16;
typedef _Float16 half8 __attribute__((ext_vector_type(8)));
typedef _Float16 half4v __attribute__((ext_vector_type(4)));
typedef float floatx4 __attribute__((ext_vector_type(4)));

#define SEQ   256
#define BATCH 128
#define HID   512
#define NL    2
#define TAPE  30
#define NG    2048   // 4*HID

__device__ __forceinline__ float fsig(float x)  { return 1.f/(1.f+__expf(-x)); }
__device__ __forceinline__ float ftanh(float x) { return 1.f - 2.f/(1.f+__expf(2.f*x)); }

// ---------------- setup: build gate-permuted fp16 weights ----------------
// Wcat row n' = 4*h + gate  maps to original row gate*512+h; cols = [W_ih | W_hh]
__global__ void k_setup_w(const float* __restrict__ W_ih, const float* __restrict__ W_hh,
                          const float* __restrict__ b_ih, const float* __restrict__ b_hh,
                          f16* __restrict__ Wcat, float* __restrict__ bsum)
{
    int idx = blockIdx.x*256 + threadIdx.x;      // exactly 2*2048*1024 threads
    int l = idx >> 21;
    int r = (idx >> 10) & 2047;
    int k = idx & 1023;
    int gate = r & 3, h = r >> 2;
    int orig = gate*HID + h;
    float wv = (k < 512) ? W_ih[((size_t)l*NG + orig)*512 + k]
                         : W_hh[((size_t)l*NG + orig)*512 + (k-512)];
    Wcat[idx] = (f16)wv;
    if (idx < NL*NG) {
        int l2 = idx >> 11, r2 = idx & 2047;
        int g2 = r2 & 3, h2 = r2 >> 2;
        int o2 = g2*HID + h2;
        bsum[idx] = b_ih[l2*NG + o2] + b_hh[l2*NG + o2];
    }
}

__global__ void k_setup_misc(const float* __restrict__ attn_wx, const float* __restrict__ attn_wh,
                             const float* __restrict__ attn_wht, const float* __restrict__ attn_v,
                             f16* __restrict__ awx, float* __restrict__ whd,
                             float* __restrict__ whtd, float* __restrict__ av)
{
    int idx = blockIdx.x*256 + threadIdx.x;      // exactly 2*512*512 threads
    awx[idx] = (f16)attn_wx[idx];
    if (idx < NL*HID) {
        int l = idx >> 9, h = idx & 511;
        whd[idx]  = attn_wh[((size_t)l*HID + h)*HID + h];   // diagonal
        whtd[idx] = attn_wht[((size_t)l*HID + h)*HID + h];  // diagonal
        av[idx]   = attn_v[idx];
    }
}

__global__ void k_xs16(const float* __restrict__ x, f16* __restrict__ o)
{
    size_t i = ((size_t)blockIdx.x*256 + threadIdx.x)*4;
    float4 v = *(const float4*)(x + i);
    half4v h; h[0]=(f16)v.x; h[1]=(f16)v.y; h[2]=(f16)v.z; h[3]=(f16)v.w;
    *(half4v*)(o + i) = h;
}

#define MFMA4(af, bf) do { \
    acc[0][0] = __builtin_amdgcn_mfma_f32_16x16x32_f16(af[0], bf[0], acc[0][0], 0, 0, 0); \
    acc[0][1] = __builtin_amdgcn_mfma_f32_16x16x32_f16(af[0], bf[1], acc[0][1], 0, 0, 0); \
    acc[1][0] = __builtin_amdgcn_mfma_f32_16x16x32_f16(af[1], bf[0], acc[1][0], 0, 0, 0); \
    acc[1][1] = __builtin_amdgcn_mfma_f32_16x16x32_f16(af[1], bf[1], acc[1][1], 0, 0, 0); \
} while(0)

// ---------------- upfront x_attn GEMM: x_attn[t,l,b,h] = sum_i awx[l,h,i]*x[t,b,i] ----
__global__ __launch_bounds__(512) void k_xattn(const f16* __restrict__ Xf,
                                               const f16* __restrict__ AWX,
                                               f16* __restrict__ XA)
{
    int nb = blockIdx.x;            // 0..7 (64 cols each)
    int t  = blockIdx.y;            // 0..255
    int l  = blockIdx.z;            // 0..1
    const f16* A  = Xf  + (size_t)t*(BATCH*512);
    const f16* Bm = AWX + (size_t)l*(512*512);
    int lane = threadIdx.x & 63, wid = threadIdx.x >> 6;
    int wm = wid >> 1, wn = wid & 1;
    int row0 = wm*32 + (lane & 15);
    int col0 = nb*64 + wn*32 + (lane & 15);
    int kc = (lane >> 4)*8;
    const f16* a_base = A  + row0*512 + kc;
    const f16* b_base = Bm + col0*512 + kc;
    floatx4 acc[2][2] = {};
    #pragma unroll 4
    for (int ks = 0; ks < 16; ks++){
        half8 af[2], bf[2];
        af[0] = *(const half8*)(a_base + ks*32);
        af[1] = *(const half8*)(a_base + 8192 + ks*32);
        bf[0] = *(const half8*)(b_base + ks*32);
        bf[1] = *(const half8*)(b_base + 8192 + ks*32);
        MFMA4(af, bf);
    }
    int rr = (lane >> 4)*4;
    #pragma unroll
    for (int mi = 0; mi < 2; mi++)
    #pragma unroll
    for (int ni = 0; ni < 2; ni++)
    #pragma unroll
    for (int j = 0; j < 4; j++){
        int brow = wm*32 + mi*16 + rr + j;
        int ch   = nb*64 + wn*32 + ni*16 + (lane & 15);
        XA[(((size_t)t*NL + l)*BATCH + brow)*HID + ch] = (f16)acc[mi][ni][j];
    }
}

// ---------------- fused gate-GEMM + LSTM cell + tape/out writes ----------------
// A = [A0 (K 0..511) | A1 (K 512..1023, optional)], B = Wcat[l] [2048][1024]
__global__ __launch_bounds__(512) void k_gemm(
    const f16* __restrict__ A0, const f16* __restrict__ A1,
    const f16* __restrict__ B,  const float* __restrict__ bsum,
    const float* __restrict__ cprev,
    float* __restrict__ h_tape, float* __restrict__ c_tape,
    int slot_base, int l,
    f16* __restrict__ h0out, float* __restrict__ dout)
{
    int y  = blockIdx.y;
    int nb = blockIdx.x;                         // 0..31, 64 gate-cols each
    A0 += (size_t)y*(BATCH*HID);
    if (h0out) h0out += (size_t)y*(BATCH*HID);
    int slot = slot_base + y;

    int tid = threadIdx.x;
    int lane = tid & 63, wid = tid >> 6;
    int wm = wid >> 1, wn = wid & 1;
    int row0 = wm*32 + (lane & 15);
    int col0 = nb*64 + wn*32 + (lane & 15);
    int kc = (lane >> 4)*8;

    const f16* a_base0 = A0 + row0*512 + kc;
    const f16* a_base1 = A1 ? (A1 + row0*512 + kc) : a_base0;
    const f16* b_base  = B + (size_t)col0*1024 + kc;
    const int nsteps = A1 ? 32 : 16;

    floatx4 acc[2][2] = {};

    auto ldA = [&](int ks, half8* fr){
        const f16* base = (ks < 16) ? (a_base0 + ks*32) : (a_base1 + (ks-16)*32);
        fr[0] = *(const half8*)(base);
        fr[1] = *(const half8*)(base + 16*512);
    };
    auto ldB = [&](int ks, half8* fr){
        const f16* base = b_base + ks*32;
        fr[0] = *(const half8*)(base);
        fr[1] = *(const half8*)(base + 16*1024);
    };

    half8 aP[2], bP[2], aQ[2], bQ[2];
    ldA(0, aP); ldB(0, bP);
    for (int ks = 0; ks < nsteps; ks += 2) {
        ldA(ks+1, aQ); ldB(ks+1, bQ);
        MFMA4(aP, bP);
        if (ks + 2 < nsteps) { ldA(ks+2, aP); ldB(ks+2, bP); }
        MFMA4(aQ, bQ);
    }

    // stage gates to LDS, add biases
    __shared__ float Cl[128][65];
    int rr = (lane >> 4)*4;
    #pragma unroll
    for (int mi = 0; mi < 2; mi++)
    #pragma unroll
    for (int ni = 0; ni < 2; ni++){
        float bias = bsum[col0 + ni*16];
        #pragma unroll
        for (int j = 0; j < 4; j++)
            Cl[wm*32 + mi*16 + rr + j][wn*32 + ni*16 + (lane & 15)] = acc[mi][ni][j] + bias;
    }
    __syncthreads();

    // LSTM cell: block owns h range [nb*16, nb*16+16), all 128 batches
    #pragma unroll
    for (int it = 0; it < 4; it++){
        int item = tid + it*512;                 // 2048 items = 128 b * 16 h
        int b = item >> 4, hl = item & 15;
        float gi = Cl[b][hl*4+0];
        float gf = Cl[b][hl*4+1];
        float gg = Cl[b][hl*4+2];
        float go = Cl[b][hl*4+3];
        int hg = nb*16 + hl;
        float cp = cprev ? cprev[b*HID + hg] : 0.f;
        float cn = fsig(gf)*cp + fsig(gi)*ftanh(gg);
        float hn = fsig(go)*ftanh(cn);
        size_t toff = (((size_t)slot*NL + l)*BATCH + b)*HID + hg;
        h_tape[toff] = hn;
        c_tape[toff] = cn;
        if (h0out) h0out[b*HID + hg] = (f16)hn;
        if (dout)  dout[b*HID + hg]  = hn;
    }
}

// ---------------- attention over the tape (one block per (l,b)) ----------------
__global__ __launch_bounds__(256, 1) void k_attn(
    const float* __restrict__ h_tape, const float* __restrict__ c_tape,
    const f16* __restrict__ x_attn,
    const float* __restrict__ whd, const float* __restrict__ whtd,
    const float* __restrict__ av,
    float* __restrict__ prev_h, float* __restrict__ prev_c,
    f16* __restrict__ prevh16, int t)
{
    int l = blockIdx.x >> 7, b = blockIdx.x & 127;
    int tid = threadIdx.x, lane = tid & 63, wv = tid >> 6;
    int h0 = tid*2;

    size_t pb = ((size_t)l*BATCH + b)*HID + h0;
    float phx = prev_h[pb], phy = prev_h[pb+1];
    const f16* xp = x_attn + (((size_t)t*NL + l)*BATCH + b)*HID + h0;
    float xax = (float)xp[0], xay = (float)xp[1];
    float wdx = whd[l*HID+h0],  wdy = whd[l*HID+h0+1];
    float wtx = whtd[l*HID+h0], wty = whtd[l*HID+h0+1];
    float vvx = av[l*HID+h0],   vvy = av[l*HID+h0+1];
    float bx = xax + phx*wtx, by = xay + phy*wty;

    // hold the whole tape slice in registers
    float2 hv[TAPE], cv[TAPE];
    #pragma unroll
    for (int p = 0; p < TAPE; p++){
        size_t off = (((size_t)p*NL + l)*BATCH + b)*HID + h0;
        hv[p] = *(const float2*)(h_tape + off);
        cv[p] = *(const float2*)(c_tape + off);
    }

    __shared__ float wpart[TAPE][4];
    #pragma unroll
    for (int p = 0; p < TAPE; p++){
        float ax = ftanh(hv[p].x*wdx + bx);
        float ay = ftanh(hv[p].y*wdy + by);
        float s = ax*vvx + ay*vvy;
        #pragma unroll
        for (int o = 32; o; o >>= 1) s += __shfl_xor(s, o);
        if (lane == 0) wpart[p][wv] = s;
    }
    __syncthreads();

    float sc[TAPE];
    float m = -1e30f;
    #pragma unroll
    for (int p = 0; p < TAPE; p++){
        sc[p] = wpart[p][0] + wpart[p][1] + wpart[p][2] + wpart[p][3];
        m = fmaxf(m, sc[p]);
    }
    float Z = 0.f;
    #pragma unroll
    for (int p = 0; p < TAPE; p++){ sc[p] = __expf(sc[p] - m); Z += sc[p]; }
    float inv = 1.f/Z;

    float ahx=0.f, ahy=0.f, acx=0.f, acy=0.f;
    #pragma unroll
    for (int p = 0; p < TAPE; p++){
        ahx += sc[p]*hv[p].x; ahy += sc[p]*hv[p].y;
        acx += sc[p]*cv[p].x; acy += sc[p]*cv[p].y;
    }
    ahx *= inv; ahy *= inv; acx *= inv; acy *= inv;

    prev_h[pb]   = ahx; prev_h[pb+1] = ahy;
    prev_c[pb]   = acx; prev_c[pb+1] = acy;
    prevh16[pb]  = (f16)ahx; prevh16[pb+1] = (f16)ahy;
}

// ---------------- host ----------------
extern "C" void kernel_launch(void* const* d_in, const int* in_sizes, int n_in,
                              void* d_out, int out_size, void* d_ws, size_t ws_size,
                              hipStream_t stream)
{
    (void)in_sizes; (void)n_in; (void)out_size; (void)ws_size;
    const float* xs       = (const float*)d_in[0];
    const float* W_ih     = (const float*)d_in[1];
    const float* W_hh     = (const float*)d_in[2];
    const float* b_ih     = (const float*)d_in[3];
    const float* b_hh     = (const float*)d_in[4];
    const float* attn_wh  = (const float*)d_in[5];
    const float* attn_wx  = (const float*)d_in[6];
    const float* attn_wht = (const float*)d_in[7];
    const float* attn_v   = (const float*)d_in[8];
    float* out = (float*)d_out;

    char* w = (char*)d_ws;
    auto alloc = [&](size_t bytes)->char*{ char* p = w; w += (bytes + 255) & ~(size_t)255; return p; };
    f16*   Wcat   = (f16*)  alloc((size_t)NL*NG*1024*2);      // 8.4 MB
    float* bsum   = (float*)alloc((size_t)NL*NG*4);
    f16*   awx    = (f16*)  alloc((size_t)NL*HID*HID*2);      // 1 MB
    float* whd    = (float*)alloc((size_t)NL*HID*4);
    float* whtd   = (float*)alloc((size_t)NL*HID*4);
    float* av     = (float*)alloc((size_t)NL*HID*4);
    f16*   xsf    = (f16*)  alloc((size_t)SEQ*BATCH*HID*2);   // 33.5 MB
    f16*   xattn  = (f16*)  alloc((size_t)SEQ*NL*BATCH*HID*2);// 67 MB
    float* h_tape = (float*)alloc((size_t)TAPE*NL*BATCH*HID*4);// 15.7 MB
    float* c_tape = (float*)alloc((size_t)TAPE*NL*BATCH*HID*4);// 15.7 MB
    float* prevh  = (float*)alloc((size_t)NL*BATCH*HID*4);
    float* prevc  = (float*)alloc((size_t)NL*BATCH*HID*4);
    f16*   prevh16= (f16*)  alloc((size_t)NL*BATCH*HID*2);
    f16*   h0all  = (f16*)  alloc((size_t)TAPE*BATCH*HID*2);  // fill layer-0 outputs

    hipMemsetAsync(prevh,   0, (size_t)NL*BATCH*HID*4, stream);
    hipMemsetAsync(prevh16, 0, (size_t)NL*BATCH*HID*2, stream);

    k_setup_w   <<<dim3(16384), dim3(256), 0, stream>>>(W_ih, W_hh, b_ih, b_hh, Wcat, bsum);
    k_setup_misc<<<dim3(2048),  dim3(256), 0, stream>>>(attn_wx, attn_wh, attn_wht, attn_v, awx, whd, whtd, av);
    k_xs16      <<<dim3(16384), dim3(256), 0, stream>>>(xs, xsf);
    k_xattn     <<<dim3(8, SEQ, NL), dim3(512), 0, stream>>>(xsf, awx, xattn);

    // tape fill: first TAPE steps, zero state, independent over t
    k_gemm<<<dim3(32, TAPE), dim3(512), 0, stream>>>(xsf, nullptr, Wcat, bsum, nullptr,
                                                     h_tape, c_tape, 0, 0, h0all, nullptr);
    k_gemm<<<dim3(32, TAPE), dim3(512), 0, stream>>>(h0all, nullptr, Wcat + (size_t)NG*1024, bsum + NG,
                                                     nullptr, h_tape, c_tape, 0, 1, nullptr, nullptr);

    // main scan
    for (int t = TAPE; t < SEQ; ++t) {
        k_attn<<<dim3(NL*BATCH), dim3(256), 0, stream>>>(h_tape, c_tape, xattn, whd, whtd, av,
                                                         prevh, prevc, prevh16, t);
        k_gemm<<<dim3(32, 1), dim3(512), 0, stream>>>(xsf + (size_t)t*BATCH*HID, prevh16,
                                                      Wcat, bsum, prevc,
                                                      h_tape, c_tape, t % TAPE, 0, h0all, nullptr);
        k_gemm<<<dim3(32, 1), dim3(512), 0, stream>>>(h0all, prevh16 + BATCH*HID,
                                                      Wcat + (size_t)NG*1024, bsum + NG,
                                                      prevc + BATCH*HID,
                                                      h_tape, c_tape, t % TAPE, 1,
                                                      nullptr, out + (size_t)((t-16) % TAPE)*BATCH*HID);
    }
}

// Round 3
// 18131.300 us; speedup vs baseline: 1.0210x; 1.0210x over previous
//
#include <hip/hip_runtime.h>
#include <hip/hip_fp16.h>
#include <hip/hip_cooperative_groups.h>

namespace cg = cooperative_groups;

typedef _Float16 f16;
typedef _Float16 half8 __attribute__((ext_vector_type(8)));
typedef _Float16 half4v __attribute__((ext_vector_type(4)));
typedef _Float16 f16x2 __attribute__((ext_vector_type(2)));
typedef float floatx4 __attribute__((ext_vector_type(4)));

#define SEQ   256
#define BATCH 128
#define HID   512
#define NL    2
#define TAPE  30
#define NG    2048   // 4*HID

__device__ __forceinline__ float fsig(float x)  { return 1.f/(1.f+__expf(-x)); }
__device__ __forceinline__ float ftanh(float x) { return 1.f - 2.f/(1.f+__expf(2.f*x)); }

// ---------------- setup: gate-permuted fp16 weights ----------------
__global__ void k_setup_w(const float* __restrict__ W_ih, const float* __restrict__ W_hh,
                          const float* __restrict__ b_ih, const float* __restrict__ b_hh,
                          f16* __restrict__ Wcat, float* __restrict__ bsum)
{
    int idx = blockIdx.x*256 + threadIdx.x;      // 2*2048*1024 threads
    int l = idx >> 21;
    int r = (idx >> 10) & 2047;
    int k = idx & 1023;
    int gate = r & 3, h = r >> 2;
    int orig = gate*HID + h;
    float wv = (k < 512) ? W_ih[((size_t)l*NG + orig)*512 + k]
                         : W_hh[((size_t)l*NG + orig)*512 + (k-512)];
    Wcat[idx] = (f16)wv;
    if (idx < NL*NG) {
        int l2 = idx >> 11, r2 = idx & 2047;
        int g2 = r2 & 3, h2 = r2 >> 2;
        int o2 = g2*HID + h2;
        bsum[idx] = b_ih[l2*NG + o2] + b_hh[l2*NG + o2];
    }
}

__global__ void k_setup_misc(const float* __restrict__ attn_wx, const float* __restrict__ attn_wh,
                             const float* __restrict__ attn_wht, const float* __restrict__ attn_v,
                             f16* __restrict__ awx, float* __restrict__ whd,
                             float* __restrict__ whtd, float* __restrict__ av)
{
    int idx = blockIdx.x*256 + threadIdx.x;      // 2*512*512 threads
    awx[idx] = (f16)attn_wx[idx];
    if (idx < NL*HID) {
        int l = idx >> 9, h = idx & 511;
        whd[idx]  = attn_wh[((size_t)l*HID + h)*HID + h];
        whtd[idx] = attn_wht[((size_t)l*HID + h)*HID + h];
        av[idx]   = attn_v[idx];
    }
}

__global__ void k_xs16(const float* __restrict__ x, f16* __restrict__ o)
{
    size_t i = ((size_t)blockIdx.x*256 + threadIdx.x)*4;
    float4 v = *(const float4*)(x + i);
    half4v h; h[0]=(f16)v.x; h[1]=(f16)v.y; h[2]=(f16)v.z; h[3]=(f16)v.w;
    *(half4v*)(o + i) = h;
}

#define MFMA4(af, bf) do { \
    acc[0][0] = __builtin_amdgcn_mfma_f32_16x16x32_f16(af[0], bf[0], acc[0][0], 0, 0, 0); \
    acc[0][1] = __builtin_amdgcn_mfma_f32_16x16x32_f16(af[0], bf[1], acc[0][1], 0, 0, 0); \
    acc[1][0] = __builtin_amdgcn_mfma_f32_16x16x32_f16(af[1], bf[0], acc[1][0], 0, 0, 0); \
    acc[1][1] = __builtin_amdgcn_mfma_f32_16x16x32_f16(af[1], bf[1], acc[1][1], 0, 0, 0); \
} while(0)

// ---------------- x_attn precompute ----------------
__global__ __launch_bounds__(512) void k_xattn(const f16* __restrict__ Xf,
                                               const f16* __restrict__ AWX,
                                               f16* __restrict__ XA)
{
    int nb = blockIdx.x;            // 0..7
    int t  = blockIdx.y;            // 0..255
    int l  = blockIdx.z;            // 0..1
    const f16* A  = Xf  + (size_t)t*(BATCH*512);
    const f16* Bm = AWX + (size_t)l*(512*512);
    int lane = threadIdx.x & 63, wid = threadIdx.x >> 6;
    int wm = wid >> 1, wn = wid & 1;
    int row0 = wm*32 + (lane & 15);
    int col0 = nb*64 + wn*32 + (lane & 15);
    int kc = (lane >> 4)*8;
    const f16* a_base = A  + row0*512 + kc;
    const f16* b_base = Bm + col0*512 + kc;
    floatx4 acc[2][2] = {};
    #pragma unroll 4
    for (int ks = 0; ks < 16; ks++){
        half8 af[2], bf[2];
        af[0] = *(const half8*)(a_base + ks*32);
        af[1] = *(const half8*)(a_base + 8192 + ks*32);
        bf[0] = *(const half8*)(b_base + ks*32);
        bf[1] = *(const half8*)(b_base + 8192 + ks*32);
        MFMA4(af, bf);
    }
    int rr = (lane >> 4)*4;
    #pragma unroll
    for (int mi = 0; mi < 2; mi++)
    #pragma unroll
    for (int ni = 0; ni < 2; ni++)
    #pragma unroll
    for (int j = 0; j < 4; j++){
        int brow = wm*32 + mi*16 + rr + j;
        int ch   = nb*64 + wn*32 + ni*16 + (lane & 15);
        XA[(((size_t)t*NL + l)*BATCH + brow)*HID + ch] = (f16)acc[mi][ni][j];
    }
}

// ---------------- tape fill (zero initial state, K=512) ----------------
__global__ __launch_bounds__(512) void k_fill(const f16* __restrict__ A0all,
                                              const f16* __restrict__ B,
                                              const float* __restrict__ bsum_l,
                                              f16* __restrict__ htape16, float* __restrict__ ctape,
                                              int l, f16* __restrict__ h0out)
{
    int y  = blockIdx.y;                         // step 0..29 (== slot)
    int nb = blockIdx.x;                         // 0..31
    const f16* A0 = A0all + (size_t)y*(BATCH*HID);
    if (h0out) h0out += (size_t)y*(BATCH*HID);

    int tid = threadIdx.x, lane = tid & 63, wid = tid >> 6;
    int wm = wid >> 1, wn = wid & 1;
    int row0 = wm*32 + (lane & 15);
    int col0 = nb*64 + wn*32 + (lane & 15);
    int kc = (lane >> 4)*8;
    const f16* a_base = A0 + row0*512 + kc;
    const f16* b_base = B + (size_t)col0*1024 + kc;

    floatx4 acc[2][2] = {};
    #pragma unroll
    for (int ks = 0; ks < 16; ks++){
        half8 af[2], bf[2];
        af[0] = *(const half8*)(a_base + ks*32);
        af[1] = *(const half8*)(a_base + 16*512 + ks*32);
        bf[0] = *(const half8*)(b_base + ks*32);
        bf[1] = *(const half8*)(b_base + (size_t)16*1024 + ks*32);
        MFMA4(af, bf);
    }

    __shared__ float Cl[128][65];
    int rr = (lane >> 4)*4;
    #pragma unroll
    for (int mi = 0; mi < 2; mi++)
    #pragma unroll
    for (int ni = 0; ni < 2; ni++){
        float bias = bsum_l[col0 + ni*16];
        #pragma unroll
        for (int j = 0; j < 4; j++)
            Cl[wm*32 + mi*16 + rr + j][wn*32 + ni*16 + (lane & 15)] = acc[mi][ni][j] + bias;
    }
    __syncthreads();

    #pragma unroll
    for (int it = 0; it < 4; it++){
        int item = tid + it*512;
        int b = item >> 4, hl = item & 15;
        float gi = Cl[b][hl*4+0];
        float gg = Cl[b][hl*4+2];
        float go = Cl[b][hl*4+3];
        int hg = nb*16 + hl;
        float cn = fsig(gi)*ftanh(gg);           // cprev == 0
        float hn = fsig(go)*ftanh(cn);
        size_t toff = (((size_t)y*NL + l)*BATCH + b)*HID + hg;
        htape16[toff] = (f16)hn;
        ctape[toff]   = cn;
        if (h0out) h0out[b*HID + hg] = (f16)hn;
    }
}

// ---------------- persistent cooperative scan kernel ----------------
struct SArgs {
    const f16* xsf; const f16* xattn; const f16* Wcat; const float* bsum;
    const float* whd; const float* whtd; const float* av;
    f16* htape16; float* ctape;
    float* prevh; float* prevc; f16* prevh16;
    f16* h016; float* out;
};

__global__ __launch_bounds__(256, 1) void k_scan(SArgs A)
{
    // 64 KiB exactly: GEMM blocks use it as weights; attn blocks as wpart.
    __shared__ __align__(16) unsigned char smem_raw[32*1024*2];
    f16* Wsh = (f16*)smem_raw;
    float (*wpart)[4] = (float (*)[4])smem_raw;

    cg::grid_group grid = cg::this_grid();
    const int blk = blockIdx.x;
    const int tid = threadIdx.x;
    const bool isAttn = blk >= 128;
    const int gl = (blk >> 6) & 1;       // gemm blocks: 0..63 -> layer0, 64..127 -> layer1
    const int cb = blk & 63;             // 32 gate-cols each
    const size_t BH = (size_t)BATCH*HID;

    // ---- GEMM role: 128 rows x 32 cols, this layer's weights LDS-resident ----
    auto do_gemm = [&](const f16* A0base, const f16* A1base, int l, int slot, float* outp){
        int lane = tid & 63, wv = tid >> 6;   // 4 waves x 32 rows
        int rowT = wv*32;
        int row0 = rowT + (lane & 15);
        int kc = (lane >> 4)*8;
        const f16* a0 = A0base + row0*512 + kc;
        const f16* a1 = A1base + row0*512 + kc;
        int colL0 = lane & 15;
        int b0 = colL0 << 10;
        int b1 = (colL0 + 16) << 10;
        int sw = (colL0 & 7) << 3;
        floatx4 acc[2][2] = {};              // [mi rows][ni cols]
        #pragma unroll
        for (int ks = 0; ks < 32; ks++){
            const f16* ab = (ks < 16) ? (a0 + ks*32) : (a1 + (ks-16)*32);
            half8 af[2], bf[2];
            af[0] = *(const half8*)ab;
            af[1] = *(const half8*)(ab + 16*512);
            int kx = (kc + ks*32) ^ sw;
            bf[0] = *(const half8*)&Wsh[b0 + kx];
            bf[1] = *(const half8*)&Wsh[b1 + kx];
            MFMA4(af, bf);
        }
        // epilogue: intra-wave gate transpose via shfl (quad = 4 gates of one h)
        const float* cprev_l = A.prevc + (size_t)l*BH;
        int baseLane = lane & 60;
        int rr = (lane >> 4) << 2;
        #pragma unroll
        for (int mi = 0; mi < 2; mi++)
        #pragma unroll
        for (int ni = 0; ni < 2; ni++){
            int colL = ni*16 + (lane & 15);
            int colG = cb*32 + colL;
            float bias = A.bsum[l*NG + colG];
            int hG = cb*8 + (colL >> 2);
            #pragma unroll
            for (int j = 0; j < 4; j++){
                float g  = acc[mi][ni][j] + bias;
                float gi = __shfl(g, baseLane + 0);
                float gf = __shfl(g, baseLane + 1);
                float gg = __shfl(g, baseLane + 2);
                float go = __shfl(g, baseLane + 3);
                int row = rowT + mi*16 + rr + j;
                float cp = cprev_l[row*HID + hG];
                float cn = fsig(gf)*cp + fsig(gi)*ftanh(gg);
                float hn = fsig(go)*ftanh(cn);
                size_t toff = (((size_t)slot*NL + l)*BATCH + row)*HID + hG;
                int role = lane & 3;
                if (role == 0)      A.htape16[toff] = (f16)hn;
                else if (role == 1) A.ctape[toff] = cn;
                else if (role == 2){
                    if (l == 0) A.h016[(size_t)row*HID + hG] = (f16)hn;
                    else        outp[(size_t)row*HID + hG]   = hn;
                }
            }
        }
    };

    // ---- attention role: one (l,b) pair, 2 h per thread, tape in registers ----
    auto do_attn = [&](int l, int t){
        int b = blk - 128;
        int lane = tid & 63, wv = tid >> 6;
        int h0 = tid*2;
        size_t pb = ((size_t)l*BATCH + b)*HID + h0;
        float phx = A.prevh[pb], phy = A.prevh[pb+1];
        const f16* xp = A.xattn + (((size_t)t*NL + l)*BATCH + b)*HID + h0;
        float xax = (float)xp[0], xay = (float)xp[1];
        int hw = l*HID + h0;
        float wdx = A.whd[hw],  wdy = A.whd[hw+1];
        float wtx = A.whtd[hw], wty = A.whtd[hw+1];
        float vvx = A.av[hw],   vvy = A.av[hw+1];
        float bx = xax + phx*wtx, by = xay + phy*wty;

        float hvx[TAPE], hvy[TAPE]; float2 cvv[TAPE];
        #pragma unroll
        for (int p = 0; p < TAPE; p++){
            size_t off = (((size_t)p*NL + l)*BATCH + b)*HID + h0;
            f16x2 hh = *(const f16x2*)(A.htape16 + off);
            hvx[p] = (float)hh[0]; hvy[p] = (float)hh[1];
            cvv[p] = *(const float2*)(A.ctape + off);
        }
        #pragma unroll
        for (int p = 0; p < TAPE; p++){
            float ax = ftanh(hvx[p]*wdx + bx);
            float ay = ftanh(hvy[p]*wdy + by);
            float s = ax*vvx + ay*vvy;
            #pragma unroll
            for (int o = 32; o; o >>= 1) s += __shfl_xor(s, o);
            if (lane == 0) wpart[p][wv] = s;
        }
        __syncthreads();
        float sc[TAPE]; float m = -1e30f;
        #pragma unroll
        for (int p = 0; p < TAPE; p++){
            sc[p] = wpart[p][0] + wpart[p][1] + wpart[p][2] + wpart[p][3];
            m = fmaxf(m, sc[p]);
        }
        float Z = 0.f;
        #pragma unroll
        for (int p = 0; p < TAPE; p++){ sc[p] = __expf(sc[p] - m); Z += sc[p]; }
        float inv = 1.f/Z;
        float ahx=0.f, ahy=0.f, acx=0.f, acy=0.f;
        #pragma unroll
        for (int p = 0; p < TAPE; p++){
            ahx += sc[p]*hvx[p]; ahy += sc[p]*hvy[p];
            acx += sc[p]*cvv[p].x; acy += sc[p]*cvv[p].y;
        }
        ahx *= inv; ahy *= inv; acx *= inv; acy *= inv;
        A.prevh[pb]   = ahx; A.prevh[pb+1] = ahy;
        A.prevc[pb]   = acx; A.prevc[pb+1] = acy;
        f16x2 ph; ph[0] = (f16)ahx; ph[1] = (f16)ahy;
        *(f16x2*)(A.prevh16 + pb) = ph;
    };

    // ---- prologue: gemm blocks load their layer's 32 cols; attn does attn_l0(TAPE) ----
    if (!isAttn){
        const f16* src = A.Wcat + ((size_t)gl*NG + (size_t)cb*32)*1024;
        for (int i = tid; i < 4096; i += 256){   // 8 f16 per iter
            int c = i >> 7;
            int k = (i & 127)*8;
            int dst = (c << 10) | (k ^ ((c & 7) << 3));
            *(half8*)&Wsh[dst] = *(const half8*)(src + ((size_t)c << 10) + k);
        }
    } else {
        do_attn(0, TAPE);
    }
    grid.sync();

    // ---- main scan: 2 grid syncs / step ----
    for (int t = TAPE; t < SEQ; ++t){
        // Phase A: gemm_l0(t) ∥ attn_l1(t)
        if (isAttn) do_attn(1, t);
        else if (gl == 0) do_gemm(A.xsf + (size_t)t*BH, A.prevh16, 0, t % TAPE, nullptr);
        grid.sync();
        // Phase B: gemm_l1(t) ∥ attn_l0(t+1)
        if (isAttn) { if (t + 1 < SEQ) do_attn(0, t + 1); }
        else if (gl == 1) do_gemm(A.h016, A.prevh16 + BH, 1, t % TAPE,
                                  A.out + (size_t)((t - 16) % TAPE)*BH);
        grid.sync();
    }
}

// ---------------- fallback kernels (round-1 proven path, fp16 h-tape) ----------------
__global__ __launch_bounds__(512) void k_gemm_fb(
    const f16* __restrict__ A0, const f16* __restrict__ A1,
    const f16* __restrict__ B,  const float* __restrict__ bsum,
    const float* __restrict__ cprev,
    f16* __restrict__ htape16, float* __restrict__ ctape,
    int slot, int l,
    f16* __restrict__ h0out, float* __restrict__ dout)
{
    int nb = blockIdx.x;                         // 0..31
    int tid = threadIdx.x, lane = tid & 63, wid = tid >> 6;
    int wm = wid >> 1, wn = wid & 1;
    int row0 = wm*32 + (lane & 15);
    int col0 = nb*64 + wn*32 + (lane & 15);
    int kc = (lane >> 4)*8;
    const f16* a_base0 = A0 + row0*512 + kc;
    const f16* a_base1 = A1 + row0*512 + kc;
    const f16* b_base  = B + (size_t)col0*1024 + kc;

    floatx4 acc[2][2] = {};
    #pragma unroll
    for (int ks = 0; ks < 32; ks++){
        const f16* ab = (ks < 16) ? (a_base0 + ks*32) : (a_base1 + (ks-16)*32);
        half8 af[2], bf[2];
        af[0] = *(const half8*)ab;
        af[1] = *(const half8*)(ab + 16*512);
        bf[0] = *(const half8*)(b_base + ks*32);
        bf[1] = *(const half8*)(b_base + (size_t)16*1024 + ks*32);
        MFMA4(af, bf);
    }

    __shared__ float Cl[128][65];
    int rr = (lane >> 4)*4;
    #pragma unroll
    for (int mi = 0; mi < 2; mi++)
    #pragma unroll
    for (int ni = 0; ni < 2; ni++){
        float bias = bsum[col0 + ni*16];
        #pragma unroll
        for (int j = 0; j < 4; j++)
            Cl[wm*32 + mi*16 + rr + j][wn*32 + ni*16 + (lane & 15)] = acc[mi][ni][j] + bias;
    }
    __syncthreads();

    #pragma unroll
    for (int it = 0; it < 4; it++){
        int item = tid + it*512;
        int b = item >> 4, hl = item & 15;
        float gi = Cl[b][hl*4+0];
        float gf = Cl[b][hl*4+1];
        float gg = Cl[b][hl*4+2];
        float go = Cl[b][hl*4+3];
        int hg = nb*16 + hl;
        float cp = cprev[b*HID + hg];
        float cn = fsig(gf)*cp + fsig(gi)*ftanh(gg);
        float hn = fsig(go)*ftanh(cn);
        size_t toff = (((size_t)slot*NL + l)*BATCH + b)*HID + hg;
        htape16[toff] = (f16)hn;
        ctape[toff]   = cn;
        if (h0out) h0out[b*HID + hg] = (f16)hn;
        if (dout)  dout[b*HID + hg]  = hn;
    }
}

__global__ __launch_bounds__(256, 1) void k_attn_fb(
    const f16* __restrict__ htape16, const float* __restrict__ ctape,
    const f16* __restrict__ x_attn,
    const float* __restrict__ whd, const float* __restrict__ whtd,
    const float* __restrict__ av,
    float* __restrict__ prev_h, float* __restrict__ prev_c,
    f16* __restrict__ prevh16, int t)
{
    int l = blockIdx.x >> 7, b = blockIdx.x & 127;
    int tid = threadIdx.x, lane = tid & 63, wv = tid >> 6;
    int h0 = tid*2;

    size_t pb = ((size_t)l*BATCH + b)*HID + h0;
    float phx = prev_h[pb], phy = prev_h[pb+1];
    const f16* xp = x_attn + (((size_t)t*NL + l)*BATCH + b)*HID + h0;
    float xax = (float)xp[0], xay = (float)xp[1];
    float wdx = whd[l*HID+h0],  wdy = whd[l*HID+h0+1];
    float wtx = whtd[l*HID+h0], wty = whtd[l*HID+h0+1];
    float vvx = av[l*HID+h0],   vvy = av[l*HID+h0+1];
    float bx = xax + phx*wtx, by = xay + phy*wty;

    float hvx[TAPE], hvy[TAPE]; float2 cvv[TAPE];
    #pragma unroll
    for (int p = 0; p < TAPE; p++){
        size_t off = (((size_t)p*NL + l)*BATCH + b)*HID + h0;
        f16x2 hh = *(const f16x2*)(htape16 + off);
        hvx[p] = (float)hh[0]; hvy[p] = (float)hh[1];
        cvv[p] = *(const float2*)(ctape + off);
    }

    __shared__ float wpart[TAPE][4];
    #pragma unroll
    for (int p = 0; p < TAPE; p++){
        float ax = ftanh(hvx[p]*wdx + bx);
        float ay = ftanh(hvy[p]*wdy + by);
        float s = ax*vvx + ay*vvy;
        #pragma unroll
        for (int o = 32; o; o >>= 1) s += __shfl_xor(s, o);
        if (lane == 0) wpart[p][wv] = s;
    }
    __syncthreads();

    float sc[TAPE]; float m = -1e30f;
    #pragma unroll
    for (int p = 0; p < TAPE; p++){
        sc[p] = wpart[p][0] + wpart[p][1] + wpart[p][2] + wpart[p][3];
        m = fmaxf(m, sc[p]);
    }
    float Z = 0.f;
    #pragma unroll
    for (int p = 0; p < TAPE; p++){ sc[p] = __expf(sc[p] - m); Z += sc[p]; }
    float inv = 1.f/Z;

    float ahx=0.f, ahy=0.f, acx=0.f, acy=0.f;
    #pragma unroll
    for (int p = 0; p < TAPE; p++){
        ahx += sc[p]*hvx[p]; ahy += sc[p]*hvy[p];
        acx += sc[p]*cvv[p].x; acy += sc[p]*cvv[p].y;
    }
    ahx *= inv; ahy *= inv; acx *= inv; acy *= inv;

    prev_h[pb]   = ahx; prev_h[pb+1] = ahy;
    prev_c[pb]   = acx; prev_c[pb+1] = acy;
    prevh16[pb]  = (f16)ahx; prevh16[pb+1] = (f16)ahy;
}

// ---------------- host ----------------
extern "C" void kernel_launch(void* const* d_in, const int* in_sizes, int n_in,
                              void* d_out, int out_size, void* d_ws, size_t ws_size,
                              hipStream_t stream)
{
    (void)in_sizes; (void)n_in; (void)out_size; (void)ws_size;
    const float* xs       = (const float*)d_in[0];
    const float* W_ih     = (const float*)d_in[1];
    const float* W_hh     = (const float*)d_in[2];
    const float* b_ih     = (const float*)d_in[3];
    const float* b_hh     = (const float*)d_in[4];
    const float* attn_wh  = (const float*)d_in[5];
    const float* attn_wx  = (const float*)d_in[6];
    const float* attn_wht = (const float*)d_in[7];
    const float* attn_v   = (const float*)d_in[8];
    float* out = (float*)d_out;

    char* w = (char*)d_ws;
    auto alloc = [&](size_t bytes)->char*{ char* p = w; w += (bytes + 255) & ~(size_t)255; return p; };
    f16*   Wcat    = (f16*)  alloc((size_t)NL*NG*1024*2);
    float* bsum    = (float*)alloc((size_t)NL*NG*4);
    f16*   awx     = (f16*)  alloc((size_t)NL*HID*HID*2);
    float* whd     = (float*)alloc((size_t)NL*HID*4);
    float* whtd    = (float*)alloc((size_t)NL*HID*4);
    float* av      = (float*)alloc((size_t)NL*HID*4);
    f16*   xsf     = (f16*)  alloc((size_t)SEQ*BATCH*HID*2);
    f16*   xattn   = (f16*)  alloc((size_t)SEQ*NL*BATCH*HID*2);
    f16*   htape16 = (f16*)  alloc((size_t)TAPE*NL*BATCH*HID*2);
    float* ctape   = (float*)alloc((size_t)TAPE*NL*BATCH*HID*4);
    float* prevh   = (float*)alloc((size_t)NL*BATCH*HID*4);
    float* prevc   = (float*)alloc((size_t)NL*BATCH*HID*4);
    f16*   prevh16 = (f16*)  alloc((size_t)NL*BATCH*HID*2);
    f16*   h016    = (f16*)  alloc((size_t)BATCH*HID*2);
    f16*   h0all   = (f16*)  alloc((size_t)TAPE*BATCH*HID*2);
    const size_t BH = (size_t)BATCH*HID;

    hipMemsetAsync(prevh, 0, (size_t)NL*BATCH*HID*4, stream);

    k_setup_w   <<<dim3(16384), dim3(256), 0, stream>>>(W_ih, W_hh, b_ih, b_hh, Wcat, bsum);
    k_setup_misc<<<dim3(2048),  dim3(256), 0, stream>>>(attn_wx, attn_wh, attn_wht, attn_v, awx, whd, whtd, av);
    k_xs16      <<<dim3(16384), dim3(256), 0, stream>>>(xs, xsf);
    k_xattn     <<<dim3(8, SEQ, NL), dim3(512), 0, stream>>>(xsf, awx, xattn);

    k_fill<<<dim3(32, TAPE), dim3(512), 0, stream>>>(xsf, Wcat, bsum, htape16, ctape, 0, h0all);
    k_fill<<<dim3(32, TAPE), dim3(512), 0, stream>>>(h0all, Wcat + (size_t)NG*1024, bsum + NG,
                                                     htape16, ctape, 1, nullptr);

    // ---- pre-flight the cooperative launch (pure host queries, capture-safe) ----
    int dev = 0; hipGetDevice(&dev);
    int coopAttr = 0;
    hipDeviceGetAttribute(&coopAttr, hipDeviceAttributeCooperativeLaunch, dev);
    int numCU = 0;
    hipDeviceGetAttribute(&numCU, hipDeviceAttributeMultiprocessorCount, dev);
    int maxBlk = 0;
    hipOccupancyMaxActiveBlocksPerMultiprocessor(&maxBlk, k_scan, 256, 0);
    bool useCoop = (coopAttr != 0) && (maxBlk >= 1) && ((long)maxBlk * numCU >= 256);

    if (useCoop) {
        SArgs sa;
        sa.xsf = xsf; sa.xattn = xattn; sa.Wcat = Wcat; sa.bsum = bsum;
        sa.whd = whd; sa.whtd = whtd; sa.av = av;
        sa.htape16 = htape16; sa.ctape = ctape;
        sa.prevh = prevh; sa.prevc = prevc; sa.prevh16 = prevh16;
        sa.h016 = h016; sa.out = out;
        void* kargs[] = { &sa };
        hipLaunchCooperativeKernel((const void*)k_scan, dim3(256), dim3(256), kargs, 0, stream);
    } else {
        // proven multi-kernel path
        for (int t = TAPE; t < SEQ; ++t) {
            k_attn_fb<<<dim3(NL*BATCH), dim3(256), 0, stream>>>(htape16, ctape, xattn, whd, whtd, av,
                                                                prevh, prevc, prevh16, t);
            k_gemm_fb<<<dim3(32), dim3(512), 0, stream>>>(xsf + (size_t)t*BH, prevh16,
                                                          Wcat, bsum, prevc,
                                                          htape16, ctape, t % TAPE, 0, h016, nullptr);
            k_gemm_fb<<<dim3(32), dim3(512), 0, stream>>>(h016, prevh16 + BH,
                                                          Wcat + (size_t)NG*1024, bsum + NG,
                                                          prevc + BH,
                                                          htape16, ctape, t % TAPE, 1,
                                                          nullptr, out + (size_t)((t-16) % TAPE)*BH);
        }
    }
}

// Round 4
// 12143.264 us; speedup vs baseline: 1.5245x; 1.4931x over previous
//
#include <hip/hip_runtime.h>
#include <hip/hip_fp16.h>

typedef _Float16 f16;
typedef _Float16 half8 __attribute__((ext_vector_type(8)));
typedef _Float16 half4v __attribute__((ext_vector_type(4)));
typedef float floatx4 __attribute__((ext_vector_type(4)));
typedef unsigned long long u64;

#define SEQ   256
#define BATCH 128
#define HID   512
#define NL    2
#define TAPE  30
#define NG    2048   // 4*HID
#define NBLK  256

__device__ __forceinline__ float fsig(float x)  { return 1.f/(1.f+__expf(-x)); }
__device__ __forceinline__ float ftanh(float x) { return 1.f - 2.f/(1.f+__expf(2.f*x)); }

// ---- agent-scope relaxed atomics (bypass non-coherent per-XCD L2s) ----
__device__ __forceinline__ u64 ald64(const void* p){
    return __hip_atomic_load((const u64*)p, __ATOMIC_RELAXED, __HIP_MEMORY_SCOPE_AGENT);
}
__device__ __forceinline__ void ast64(void* p, u64 v){
    __hip_atomic_store((u64*)p, v, __ATOMIC_RELAXED, __HIP_MEMORY_SCOPE_AGENT);
}
__device__ __forceinline__ float ald32f(const float* p){
    return __hip_atomic_load(p, __ATOMIC_RELAXED, __HIP_MEMORY_SCOPE_AGENT);
}
__device__ __forceinline__ void ast32(void* p, unsigned v){
    __hip_atomic_store((unsigned*)p, v, __ATOMIC_RELAXED, __HIP_MEMORY_SCOPE_AGENT);
}
__device__ __forceinline__ half8 ald_h8(const f16* p){
    union { u64 u[2]; half8 h; } c;
    c.u[0] = ald64(p); c.u[1] = ald64(p + 4);
    return c.h;
}
__device__ __forceinline__ unsigned packh2(float a, float b){
    union { f16 h[2]; unsigned u; } c; c.h[0]=(f16)a; c.h[1]=(f16)b; return c.u;
}
__device__ __forceinline__ float2 unpackh2(unsigned u){
    union { unsigned u; f16 h[2]; } c; c.u=u;
    float2 r; r.x=(float)c.h[0]; r.y=(float)c.h[1]; return r;
}

// ---- custom grid barrier: packed {gen<<32 | count}, no cache flushes ----
__device__ __forceinline__ void gridbar(u64* bar, u64 gen){
    __syncthreads();                       // drains vmcnt -> prior agent stores at L3
    if (threadIdx.x == 0){
        u64 prev = __hip_atomic_fetch_add(bar, 1ull, __ATOMIC_RELAXED, __HIP_MEMORY_SCOPE_AGENT);
        if ((prev & 0xffffffffull) == (u64)(NBLK-1)){
            __hip_atomic_store(bar, gen << 32, __ATOMIC_RELAXED, __HIP_MEMORY_SCOPE_AGENT);
        } else {
            while ((__hip_atomic_load(bar, __ATOMIC_RELAXED, __HIP_MEMORY_SCOPE_AGENT) >> 32) < gen){
                __builtin_amdgcn_s_sleep(2);
            }
        }
    }
    __syncthreads();
}

// ---------------- setup: gate-permuted fp16 weights ----------------
__global__ void k_setup_w(const float* __restrict__ W_ih, const float* __restrict__ W_hh,
                          const float* __restrict__ b_ih, const float* __restrict__ b_hh,
                          f16* __restrict__ Wcat, float* __restrict__ bsum)
{
    int idx = blockIdx.x*256 + threadIdx.x;      // 2*2048*1024 threads
    int l = idx >> 21;
    int r = (idx >> 10) & 2047;
    int k = idx & 1023;
    int gate = r & 3, h = r >> 2;
    int orig = gate*HID + h;
    float wv = (k < 512) ? W_ih[((size_t)l*NG + orig)*512 + k]
                         : W_hh[((size_t)l*NG + orig)*512 + (k-512)];
    Wcat[idx] = (f16)wv;
    if (idx < NL*NG) {
        int l2 = idx >> 11, r2 = idx & 2047;
        int g2 = r2 & 3, h2 = r2 >> 2;
        int o2 = g2*HID + h2;
        bsum[idx] = b_ih[l2*NG + o2] + b_hh[l2*NG + o2];
    }
}

__global__ void k_setup_misc(const float* __restrict__ attn_wx, const float* __restrict__ attn_wh,
                             const float* __restrict__ attn_wht, const float* __restrict__ attn_v,
                             f16* __restrict__ awx, float* __restrict__ whd,
                             float* __restrict__ whtd, float* __restrict__ av)
{
    int idx = blockIdx.x*256 + threadIdx.x;      // 2*512*512 threads
    awx[idx] = (f16)attn_wx[idx];
    if (idx < NL*HID) {
        int l = idx >> 9, h = idx & 511;
        whd[idx]  = attn_wh[((size_t)l*HID + h)*HID + h];
        whtd[idx] = attn_wht[((size_t)l*HID + h)*HID + h];
        av[idx]   = attn_v[idx];
    }
}

__global__ void k_xs16(const float* __restrict__ x, f16* __restrict__ o)
{
    size_t i = ((size_t)blockIdx.x*256 + threadIdx.x)*4;
    float4 v = *(const float4*)(x + i);
    half4v h; h[0]=(f16)v.x; h[1]=(f16)v.y; h[2]=(f16)v.z; h[3]=(f16)v.w;
    *(half4v*)(o + i) = h;
}

#define MFMA4(af, bf) do { \
    acc[0][0] = __builtin_amdgcn_mfma_f32_16x16x32_f16(af[0], bf[0], acc[0][0], 0, 0, 0); \
    acc[0][1] = __builtin_amdgcn_mfma_f32_16x16x32_f16(af[0], bf[1], acc[0][1], 0, 0, 0); \
    acc[1][0] = __builtin_amdgcn_mfma_f32_16x16x32_f16(af[1], bf[0], acc[1][0], 0, 0, 0); \
    acc[1][1] = __builtin_amdgcn_mfma_f32_16x16x32_f16(af[1], bf[1], acc[1][1], 0, 0, 0); \
} while(0)

// ---------------- x_attn precompute ----------------
__global__ __launch_bounds__(512) void k_xattn(const f16* __restrict__ Xf,
                                               const f16* __restrict__ AWX,
                                               f16* __restrict__ XA)
{
    int nb = blockIdx.x;            // 0..7
    int t  = blockIdx.y;            // 0..255
    int l  = blockIdx.z;            // 0..1
    const f16* A  = Xf  + (size_t)t*(BATCH*512);
    const f16* Bm = AWX + (size_t)l*(512*512);
    int lane = threadIdx.x & 63, wid = threadIdx.x >> 6;
    int wm = wid >> 1, wn = wid & 1;
    int row0 = wm*32 + (lane & 15);
    int col0 = nb*64 + wn*32 + (lane & 15);
    int kc = (lane >> 4)*8;
    const f16* a_base = A  + row0*512 + kc;
    const f16* b_base = Bm + col0*512 + kc;
    floatx4 acc[2][2] = {};
    #pragma unroll 4
    for (int ks = 0; ks < 16; ks++){
        half8 af[2], bf[2];
        af[0] = *(const half8*)(a_base + ks*32);
        af[1] = *(const half8*)(a_base + 8192 + ks*32);
        bf[0] = *(const half8*)(b_base + ks*32);
        bf[1] = *(const half8*)(b_base + 8192 + ks*32);
        MFMA4(af, bf);
    }
    int rr = (lane >> 4)*4;
    #pragma unroll
    for (int mi = 0; mi < 2; mi++)
    #pragma unroll
    for (int ni = 0; ni < 2; ni++)
    #pragma unroll
    for (int j = 0; j < 4; j++){
        int brow = wm*32 + mi*16 + rr + j;
        int ch   = nb*64 + wn*32 + ni*16 + (lane & 15);
        XA[(((size_t)t*NL + l)*BATCH + brow)*HID + ch] = (f16)acc[mi][ni][j];
    }
}

// ---------------- tape fill (zero initial state, K=512) ----------------
__global__ __launch_bounds__(512) void k_fill(const f16* __restrict__ A0all,
                                              const f16* __restrict__ B,
                                              const float* __restrict__ bsum_l,
                                              f16* __restrict__ htape16, float* __restrict__ ctape,
                                              int l, f16* __restrict__ h0out)
{
    int y  = blockIdx.y;                         // step 0..29 (== slot)
    int nb = blockIdx.x;                         // 0..31
    const f16* A0 = A0all + (size_t)y*(BATCH*HID);
    if (h0out) h0out += (size_t)y*(BATCH*HID);

    int tid = threadIdx.x, lane = tid & 63, wid = tid >> 6;
    int wm = wid >> 1, wn = wid & 1;
    int row0 = wm*32 + (lane & 15);
    int col0 = nb*64 + wn*32 + (lane & 15);
    int kc = (lane >> 4)*8;
    const f16* a_base = A0 + row0*512 + kc;
    const f16* b_base = B + (size_t)col0*1024 + kc;

    floatx4 acc[2][2] = {};
    #pragma unroll
    for (int ks = 0; ks < 16; ks++){
        half8 af[2], bf[2];
        af[0] = *(const half8*)(a_base + ks*32);
        af[1] = *(const half8*)(a_base + 16*512 + ks*32);
        bf[0] = *(const half8*)(b_base + ks*32);
        bf[1] = *(const half8*)(b_base + (size_t)16*1024 + ks*32);
        MFMA4(af, bf);
    }

    __shared__ float Cl[128][65];
    int rr = (lane >> 4)*4;
    #pragma unroll
    for (int mi = 0; mi < 2; mi++)
    #pragma unroll
    for (int ni = 0; ni < 2; ni++){
        float bias = bsum_l[col0 + ni*16];
        #pragma unroll
        for (int j = 0; j < 4; j++)
            Cl[wm*32 + mi*16 + rr + j][wn*32 + ni*16 + (lane & 15)] = acc[mi][ni][j] + bias;
    }
    __syncthreads();

    #pragma unroll
    for (int it = 0; it < 4; it++){
        int item = tid + it*512;
        int b = item >> 4, hl = item & 15;
        float gi = Cl[b][hl*4+0];
        float gg = Cl[b][hl*4+2];
        float go = Cl[b][hl*4+3];
        int hg = nb*16 + hl;
        float cn = fsig(gi)*ftanh(gg);           // cprev == 0
        float hn = fsig(go)*ftanh(cn);
        size_t toff = (((size_t)y*NL + l)*BATCH + b)*HID + hg;
        htape16[toff] = (f16)hn;
        ctape[toff]   = cn;
        if (h0out) h0out[b*HID + hg] = (f16)hn;
    }
}

// ---------------- persistent scan kernel ----------------
struct SArgs {
    const f16* xsf; const f16* xattn; const f16* Wcat; const float* bsum;
    const float* whd; const float* whtd; const float* av;
    const f16* htape16; const float* ctape;   // ring init (k_fill output)
    float* prevc; f16* prevh16;
    f16* h016; float2* slotstage; float* out;
    u64* bar;
};

__global__ __launch_bounds__(256, 1) void k_scan(SArgs A)
{
    __shared__ f16 Wsh[16*1024];        // 32 KiB: this block's 16 gate-cols, XOR-swizzled
    __shared__ float2 stg[128*4];       // 4 KiB epilogue staging {h,c}
    __shared__ float wpart[TAPE][4];

    const int blk = blockIdx.x;
    const int tid = threadIdx.x;
    const int lane = tid & 63, wv = tid >> 6;
    const int myl = blk >> 7;           // 0: blocks 0..127 (gemm_l0 + attn_l0), 1: 128..255
    const int cb  = blk & 127;          // gemm: 16 gate-cols -> 4 h
    const int b   = blk & 127;          // attn: batch index
    const int h0  = tid*2;              // attn: h pair
    const size_t BH = (size_t)BATCH*HID;

    // ---- weights to LDS (once) ----
    {
        const f16* src = A.Wcat + ((size_t)myl*NG + (size_t)cb*16)*1024;
        for (int i = tid; i < 2048; i += 256){
            int c = i >> 7;              // 0..15
            int k = (i & 127)*8;
            int dst = (c << 10) | (k ^ ((c & 7) << 3));
            *(half8*)&Wsh[dst] = *(const half8*)(src + ((size_t)c << 10) + k);
        }
    }

    // ---- tape ring in registers: 30 slots x {h pair, c pair} packed f16x2 ----
    unsigned ringH[TAPE], ringC[TAPE];
    float phx = 0.f, phy = 0.f;          // prev_h (this block's layer), full fp32
    #pragma unroll
    for (int p = 0; p < TAPE; p++){
        size_t off = (((size_t)p*NL + myl)*BATCH + b)*HID + h0;
        ringH[p] = *(const unsigned*)(A.htape16 + off);
        float2 cc = *(const float2*)(A.ctape + off);
        ringC[p] = packh2(cc.x, cc.y);
    }

    // ---- attention for this block's (myl, b) ----
    auto do_attn = [&](int t, bool consume){
        if (consume){
            int snew = (t-1) % TAPE;
            const float2* sl2 = A.slotstage + ((size_t)myl*BATCH + b)*HID + h0;
            union { u64 u; float2 f; } c0, c1;
            c0.u = ald64(sl2); c1.u = ald64(sl2+1);
            unsigned nh = packh2(c0.f.x, c1.f.x);
            unsigned nc = packh2(c0.f.y, c1.f.y);
            #pragma unroll
            for (int p = 0; p < TAPE; p++) if (p == snew){ ringH[p]=nh; ringC[p]=nc; }
        }
        size_t pb = ((size_t)myl*BATCH + b)*HID + h0;
        const f16* xp = A.xattn + (((size_t)t*NL + myl)*BATCH + b)*HID + h0;
        float xax = (float)xp[0], xay = (float)xp[1];
        int hw = myl*HID + h0;
        float wdx = A.whd[hw],  wdy = A.whd[hw+1];
        float wtx = A.whtd[hw], wty = A.whtd[hw+1];
        float vvx = A.av[hw],   vvy = A.av[hw+1];
        float bx = xax + phx*wtx, by = xay + phy*wty;

        float sc[TAPE];
        #pragma unroll
        for (int p = 0; p < TAPE; p++){
            float2 hv = unpackh2(ringH[p]);
            float ax = ftanh(hv.x*wdx + bx);
            float ay = ftanh(hv.y*wdy + by);
            float s = ax*vvx + ay*vvy;
            #pragma unroll
            for (int o = 32; o; o >>= 1) s += __shfl_xor(s, o);
            if (lane == 0) wpart[p][wv] = s;
        }
        __syncthreads();
        float m = -1e30f;
        #pragma unroll
        for (int p = 0; p < TAPE; p++){
            sc[p] = wpart[p][0] + wpart[p][1] + wpart[p][2] + wpart[p][3];
            m = fmaxf(m, sc[p]);
        }
        float Z = 0.f;
        #pragma unroll
        for (int p = 0; p < TAPE; p++){ sc[p] = __expf(sc[p] - m); Z += sc[p]; }
        float inv = 1.f/Z;
        float ahx=0.f, ahy=0.f, acx=0.f, acy=0.f;
        #pragma unroll
        for (int p = 0; p < TAPE; p++){
            float2 hv = unpackh2(ringH[p]);
            float2 cv = unpackh2(ringC[p]);
            ahx += sc[p]*hv.x; ahy += sc[p]*hv.y;
            acx += sc[p]*cv.x; acy += sc[p]*cv.y;
        }
        ahx*=inv; ahy*=inv; acx*=inv; acy*=inv;
        phx = ahx; phy = ahy;
        ast32(A.prevh16 + pb, packh2(ahx, ahy));
        union { float2 f; u64 u; } pc; pc.f.x = acx; pc.f.y = acy;
        ast64(A.prevc + pb, pc.u);
    };

    // ---- gemm for this block's layer: 128 rows x 16 gate-cols, K=1024 ----
    auto do_gemm = [&](const f16* A0base, bool a0ag, const f16* A1base,
                       f16* h0out, float* outp){
        int rowT = wv*32;
        int row0 = rowT + (lane & 15);
        int kc = (lane >> 4)*8;
        const f16* a0 = A0base + (size_t)row0*512 + kc;
        const f16* a1 = A1base + (size_t)row0*512 + kc;
        int colL = lane & 15;
        int bofs = colL << 10;
        int sw = (colL & 7) << 3;
        floatx4 acc0 = {0,0,0,0}, acc1 = {0,0,0,0};
        if (a0ag){
            #pragma unroll 8
            for (int ks = 0; ks < 16; ks++){
                half8 af0 = ald_h8(a0 + ks*32);
                half8 af1 = ald_h8(a0 + ks*32 + 16*512);
                int kx = (kc + ks*32) ^ sw;
                half8 bf = *(const half8*)&Wsh[bofs + kx];
                acc0 = __builtin_amdgcn_mfma_f32_16x16x32_f16(af0, bf, acc0, 0, 0, 0);
                acc1 = __builtin_amdgcn_mfma_f32_16x16x32_f16(af1, bf, acc1, 0, 0, 0);
            }
        } else {
            #pragma unroll 8
            for (int ks = 0; ks < 16; ks++){
                half8 af0 = *(const half8*)(a0 + ks*32);
                half8 af1 = *(const half8*)(a0 + ks*32 + 16*512);
                int kx = (kc + ks*32) ^ sw;
                half8 bf = *(const half8*)&Wsh[bofs + kx];
                acc0 = __builtin_amdgcn_mfma_f32_16x16x32_f16(af0, bf, acc0, 0, 0, 0);
                acc1 = __builtin_amdgcn_mfma_f32_16x16x32_f16(af1, bf, acc1, 0, 0, 0);
            }
        }
        #pragma unroll 8
        for (int ks = 0; ks < 16; ks++){
            half8 af0 = ald_h8(a1 + ks*32);
            half8 af1 = ald_h8(a1 + ks*32 + 16*512);
            int kx = (kc + (ks+16)*32) ^ sw;
            half8 bf = *(const half8*)&Wsh[bofs + kx];
            acc0 = __builtin_amdgcn_mfma_f32_16x16x32_f16(af0, bf, acc0, 0, 0, 0);
            acc1 = __builtin_amdgcn_mfma_f32_16x16x32_f16(af1, bf, acc1, 0, 0, 0);
        }
        // epilogue: quad-shfl gate transpose + cell update -> LDS stage
        const float* cprev_l = A.prevc + (size_t)myl*BH;
        int baseLane = lane & 60;
        int rr = (lane >> 4) << 2;
        int colG = cb*16 + colL;
        float bias = A.bsum[myl*NG + colG];
        int hL = colL >> 2;
        int hG = cb*4 + hL;
        #pragma unroll
        for (int mi = 0; mi < 2; mi++){
            #pragma unroll
            for (int j = 0; j < 4; j++){
                float g = (mi ? acc1[j] : acc0[j]) + bias;
                float gi = __shfl(g, baseLane+0);
                float gf = __shfl(g, baseLane+1);
                float gg = __shfl(g, baseLane+2);
                float go = __shfl(g, baseLane+3);
                int row = rowT + mi*16 + rr + j;
                float cp = ald32f(&cprev_l[(size_t)row*HID + hG]);
                float cn = fsig(gf)*cp + fsig(gi)*ftanh(gg);
                float hn = fsig(go)*ftanh(cn);
                if ((lane & 3) == 0){ float2 v; v.x=hn; v.y=cn; stg[row*4 + hL] = v; }
            }
        }
        __syncthreads();
        // packed agent stores of the new tape slot {h,c}
        float2* slot2 = A.slotstage + (size_t)myl*BH;
        #pragma unroll
        for (int e = 0; e < 2; e++){
            int idx = tid + e*256;           // 0..511 = row*4 + hh
            int row = idx >> 2, hh = idx & 3;
            union { float2 f; u64 u; } cu; cu.f = stg[idx];
            ast64(&slot2[(size_t)row*HID + cb*4 + hh], cu.u);
        }
        if (tid < 128){
            int row = tid;
            if (myl == 0){
                union { f16 h[4]; u64 u; } pk;
                pk.h[0]=(f16)stg[row*4+0].x; pk.h[1]=(f16)stg[row*4+1].x;
                pk.h[2]=(f16)stg[row*4+2].x; pk.h[3]=(f16)stg[row*4+3].x;
                ast64(h0out + (size_t)row*512 + cb*4, pk.u);
            } else {
                float4 v; v.x=stg[row*4+0].x; v.y=stg[row*4+1].x;
                          v.z=stg[row*4+2].x; v.w=stg[row*4+3].x;
                *(float4*)(outp + (size_t)row*512 + cb*4) = v;   // out: host-only, normal store
            }
        }
    };

    // ---- prologue: attn_l0(TAPE) on lower half ----
    if (myl == 0) do_attn(TAPE, false);
    u64 gen = 0;
    gridbar(A.bar, ++gen);

    // ---- main scan: 2 barriers / step, every block busy every phase ----
    for (int t = TAPE; t < SEQ; ++t){
        // Phase A: gemm_l0(t) [blocks 0..127]  ||  attn_l1(t) [blocks 128..255]
        if (myl == 0) do_gemm(A.xsf + (size_t)t*BH, false, A.prevh16, A.h016, nullptr);
        else          do_attn(t, t > TAPE);
        gridbar(A.bar, ++gen);
        // Phase B: gemm_l1(t) [blocks 128..255]  ||  attn_l0(t+1) [blocks 0..127]
        if (myl == 1) do_gemm(A.h016, true, A.prevh16 + BH, nullptr,
                              A.out + (size_t)((t-16) % TAPE)*BH);
        else if (t + 1 < SEQ) do_attn(t + 1, true);
        gridbar(A.bar, ++gen);
    }
}

// ---------------- fallback kernels (round-1 proven path, fp16 h-tape) ----------------
__global__ __launch_bounds__(512) void k_gemm_fb(
    const f16* __restrict__ A0, const f16* __restrict__ A1,
    const f16* __restrict__ B,  const float* __restrict__ bsum,
    const float* __restrict__ cprev,
    f16* __restrict__ htape16, float* __restrict__ ctape,
    int slot, int l,
    f16* __restrict__ h0out, float* __restrict__ dout)
{
    int nb = blockIdx.x;
    int tid = threadIdx.x, lane = tid & 63, wid = tid >> 6;
    int wm = wid >> 1, wn = wid & 1;
    int row0 = wm*32 + (lane & 15);
    int col0 = nb*64 + wn*32 + (lane & 15);
    int kc = (lane >> 4)*8;
    const f16* a_base0 = A0 + row0*512 + kc;
    const f16* a_base1 = A1 + row0*512 + kc;
    const f16* b_base  = B + (size_t)col0*1024 + kc;

    floatx4 acc[2][2] = {};
    #pragma unroll
    for (int ks = 0; ks < 32; ks++){
        const f16* ab = (ks < 16) ? (a_base0 + ks*32) : (a_base1 + (ks-16)*32);
        half8 af[2], bf[2];
        af[0] = *(const half8*)ab;
        af[1] = *(const half8*)(ab + 16*512);
        bf[0] = *(const half8*)(b_base + ks*32);
        bf[1] = *(const half8*)(b_base + (size_t)16*1024 + ks*32);
        MFMA4(af, bf);
    }

    __shared__ float Cl[128][65];
    int rr = (lane >> 4)*4;
    #pragma unroll
    for (int mi = 0; mi < 2; mi++)
    #pragma unroll
    for (int ni = 0; ni < 2; ni++){
        float bias = bsum[col0 + ni*16];
        #pragma unroll
        for (int j = 0; j < 4; j++)
            Cl[wm*32 + mi*16 + rr + j][wn*32 + ni*16 + (lane & 15)] = acc[mi][ni][j] + bias;
    }
    __syncthreads();

    #pragma unroll
    for (int it = 0; it < 4; it++){
        int item = tid + it*512;
        int b = item >> 4, hl = item & 15;
        float gi = Cl[b][hl*4+0];
        float gf = Cl[b][hl*4+1];
        float gg = Cl[b][hl*4+2];
        float go = Cl[b][hl*4+3];
        int hg = nb*16 + hl;
        float cp = cprev[b*HID + hg];
        float cn = fsig(gf)*cp + fsig(gi)*ftanh(gg);
        float hn = fsig(go)*ftanh(cn);
        size_t toff = (((size_t)slot*NL + l)*BATCH + b)*HID + hg;
        htape16[toff] = (f16)hn;
        ctape[toff]   = cn;
        if (h0out) h0out[b*HID + hg] = (f16)hn;
        if (dout)  dout[b*HID + hg]  = hn;
    }
}

__global__ __launch_bounds__(256, 1) void k_attn_fb(
    const f16* __restrict__ htape16, const float* __restrict__ ctape,
    const f16* __restrict__ x_attn,
    const float* __restrict__ whd, const float* __restrict__ whtd,
    const float* __restrict__ av,
    float* __restrict__ prev_h, float* __restrict__ prev_c,
    f16* __restrict__ prevh16, int t)
{
    int l = blockIdx.x >> 7, b = blockIdx.x & 127;
    int tid = threadIdx.x, lane = tid & 63, wv = tid >> 6;
    int h0 = tid*2;

    size_t pb = ((size_t)l*BATCH + b)*HID + h0;
    float phx = prev_h[pb], phy = prev_h[pb+1];
    const f16* xp = x_attn + (((size_t)t*NL + l)*BATCH + b)*HID + h0;
    float xax = (float)xp[0], xay = (float)xp[1];
    float wdx = whd[l*HID+h0],  wdy = whd[l*HID+h0+1];
    float wtx = whtd[l*HID+h0], wty = whtd[l*HID+h0+1];
    float vvx = av[l*HID+h0],   vvy = av[l*HID+h0+1];
    float bx = xax + phx*wtx, by = xay + phy*wty;

    float hvx[TAPE], hvy[TAPE]; float2 cvv[TAPE];
    #pragma unroll
    for (int p = 0; p < TAPE; p++){
        size_t off = (((size_t)p*NL + l)*BATCH + b)*HID + h0;
        unsigned hh = *(const unsigned*)(htape16 + off);
        float2 hv = unpackh2(hh);
        hvx[p] = hv.x; hvy[p] = hv.y;
        cvv[p] = *(const float2*)(ctape + off);
    }

    __shared__ float wpart[TAPE][4];
    #pragma unroll
    for (int p = 0; p < TAPE; p++){
        float ax = ftanh(hvx[p]*wdx + bx);
        float ay = ftanh(hvy[p]*wdy + by);
        float s = ax*vvx + ay*vvy;
        #pragma unroll
        for (int o = 32; o; o >>= 1) s += __shfl_xor(s, o);
        if (lane == 0) wpart[p][wv] = s;
    }
    __syncthreads();

    float sc[TAPE]; float m = -1e30f;
    #pragma unroll
    for (int p = 0; p < TAPE; p++){
        sc[p] = wpart[p][0] + wpart[p][1] + wpart[p][2] + wpart[p][3];
        m = fmaxf(m, sc[p]);
    }
    float Z = 0.f;
    #pragma unroll
    for (int p = 0; p < TAPE; p++){ sc[p] = __expf(sc[p] - m); Z += sc[p]; }
    float inv = 1.f/Z;

    float ahx=0.f, ahy=0.f, acx=0.f, acy=0.f;
    #pragma unroll
    for (int p = 0; p < TAPE; p++){
        ahx += sc[p]*hvx[p]; ahy += sc[p]*hvy[p];
        acx += sc[p]*cvv[p].x; acy += sc[p]*cvv[p].y;
    }
    ahx *= inv; ahy *= inv; acx *= inv; acy *= inv;

    prev_h[pb]   = ahx; prev_h[pb+1] = ahy;
    prev_c[pb]   = acx; prev_c[pb+1] = acy;
    prevh16[pb]  = (f16)ahx; prevh16[pb+1] = (f16)ahy;
}

// ---------------- host ----------------
extern "C" void kernel_launch(void* const* d_in, const int* in_sizes, int n_in,
                              void* d_out, int out_size, void* d_ws, size_t ws_size,
                              hipStream_t stream)
{
    (void)in_sizes; (void)n_in; (void)out_size; (void)ws_size;
    const float* xs       = (const float*)d_in[0];
    const float* W_ih     = (const float*)d_in[1];
    const float* W_hh     = (const float*)d_in[2];
    const float* b_ih     = (const float*)d_in[3];
    const float* b_hh     = (const float*)d_in[4];
    const float* attn_wh  = (const float*)d_in[5];
    const float* attn_wx  = (const float*)d_in[6];
    const float* attn_wht = (const float*)d_in[7];
    const float* attn_v   = (const float*)d_in[8];
    float* out = (float*)d_out;

    char* w = (char*)d_ws;
    auto alloc = [&](size_t bytes)->char*{ char* p = w; w += (bytes + 255) & ~(size_t)255; return p; };
    f16*   Wcat    = (f16*)   alloc((size_t)NL*NG*1024*2);
    float* bsum    = (float*) alloc((size_t)NL*NG*4);
    f16*   awx     = (f16*)   alloc((size_t)NL*HID*HID*2);
    float* whd     = (float*) alloc((size_t)NL*HID*4);
    float* whtd    = (float*) alloc((size_t)NL*HID*4);
    float* av      = (float*) alloc((size_t)NL*HID*4);
    f16*   xsf     = (f16*)   alloc((size_t)SEQ*BATCH*HID*2);
    f16*   xattn   = (f16*)   alloc((size_t)SEQ*NL*BATCH*HID*2);
    f16*   htape16 = (f16*)   alloc((size_t)TAPE*NL*BATCH*HID*2);
    float* ctape   = (float*) alloc((size_t)TAPE*NL*BATCH*HID*4);
    float* prevh   = (float*) alloc((size_t)NL*BATCH*HID*4);
    float* prevc   = (float*) alloc((size_t)NL*BATCH*HID*4);
    f16*   prevh16 = (f16*)   alloc((size_t)NL*BATCH*HID*2);
    f16*   h016    = (f16*)   alloc((size_t)BATCH*HID*2);
    f16*   h0all   = (f16*)   alloc((size_t)TAPE*BATCH*HID*2);
    float2* slotstage = (float2*)alloc((size_t)NL*BATCH*HID*8);
    u64*   bar     = (u64*)   alloc(256);
    const size_t BH = (size_t)BATCH*HID;

    hipMemsetAsync(prevh,   0, (size_t)NL*BATCH*HID*4, stream);
    hipMemsetAsync(prevc,   0, (size_t)NL*BATCH*HID*4, stream);
    hipMemsetAsync(prevh16, 0, (size_t)NL*BATCH*HID*2, stream);
    hipMemsetAsync(bar,     0, 256, stream);

    k_setup_w   <<<dim3(16384), dim3(256), 0, stream>>>(W_ih, W_hh, b_ih, b_hh, Wcat, bsum);
    k_setup_misc<<<dim3(2048),  dim3(256), 0, stream>>>(attn_wx, attn_wh, attn_wht, attn_v, awx, whd, whtd, av);
    k_xs16      <<<dim3(16384), dim3(256), 0, stream>>>(xs, xsf);
    k_xattn     <<<dim3(8, SEQ, NL), dim3(512), 0, stream>>>(xsf, awx, xattn);

    k_fill<<<dim3(32, TAPE), dim3(512), 0, stream>>>(xsf, Wcat, bsum, htape16, ctape, 0, h0all);
    k_fill<<<dim3(32, TAPE), dim3(512), 0, stream>>>(h0all, Wcat + (size_t)NG*1024, bsum + NG,
                                                     htape16, ctape, 1, nullptr);

    // ---- pre-flight the cooperative launch (pure host queries, capture-safe) ----
    int dev = 0; hipGetDevice(&dev);
    int coopAttr = 0;
    hipDeviceGetAttribute(&coopAttr, hipDeviceAttributeCooperativeLaunch, dev);
    int numCU = 0;
    hipDeviceGetAttribute(&numCU, hipDeviceAttributeMultiprocessorCount, dev);
    int maxBlk = 0;
    hipOccupancyMaxActiveBlocksPerMultiprocessor(&maxBlk, k_scan, 256, 0);
    bool useCoop = (coopAttr != 0) && (maxBlk >= 1) && ((long)maxBlk * numCU >= NBLK);

    if (useCoop) {
        SArgs sa;
        sa.xsf = xsf; sa.xattn = xattn; sa.Wcat = Wcat; sa.bsum = bsum;
        sa.whd = whd; sa.whtd = whtd; sa.av = av;
        sa.htape16 = htape16; sa.ctape = ctape;
        sa.prevc = prevc; sa.prevh16 = prevh16;
        sa.h016 = h016; sa.slotstage = slotstage; sa.out = out;
        sa.bar = bar;
        void* kargs[] = { &sa };
        hipLaunchCooperativeKernel((const void*)k_scan, dim3(NBLK), dim3(256), kargs, 0, stream);
    } else {
        // proven multi-kernel path
        for (int t = TAPE; t < SEQ; ++t) {
            k_attn_fb<<<dim3(NL*BATCH), dim3(256), 0, stream>>>(htape16, ctape, xattn, whd, whtd, av,
                                                                prevh, prevc, prevh16, t);
            k_gemm_fb<<<dim3(32), dim3(512), 0, stream>>>(xsf + (size_t)t*BH, prevh16,
                                                          Wcat, bsum, prevc,
                                                          htape16, ctape, t % TAPE, 0, h016, nullptr);
            k_gemm_fb<<<dim3(32), dim3(512), 0, stream>>>(h016, prevh16 + BH,
                                                          Wcat + (size_t)NG*1024, bsum + NG,
                                                          prevc + BH,
                                                          htape16, ctape, t % TAPE, 1,
                                                          nullptr, out + (size_t)((t-16) % TAPE)*BH);
        }
    }
}